// Round 1
// baseline (446.583 us; speedup 1.0000x reference)
//
#include <hip/hip_runtime.h>

constexpr int NTOK = 2048;
constexpr int CH   = 128;
constexpr int C4   = 32;
constexpr int NB   = 16;

typedef __attribute__((ext_vector_type(8))) __bf16 bf16x8;
typedef __attribute__((ext_vector_type(4))) float  f32x4;

__device__ __forceinline__ unsigned short f2bf(float f) {
  union { float f; unsigned u; } v; v.f = f;
  unsigned r = v.u + 0x7fffu + ((v.u >> 16) & 1u);
  return (unsigned short)(r >> 16);
}
__device__ __forceinline__ float bf2f(unsigned short h) {
  union { unsigned u; float f; } v; v.u = ((unsigned)h) << 16;
  return v.f;
}

// rowsumH[b][c] = sum_n x_h[b][c][n]   (float64, exact-ish from inputs)
__global__ __launch_bounds__(256) void rs_kernel(const float* __restrict__ x_h,
                                                 double* __restrict__ rowsumH) {
  const int t = threadIdx.x;
  const int c0 = blockIdx.x * 16;
  const int b = blockIdx.y;
  __shared__ double red[4];
  for (int cl = 0; cl < 16; ++cl) {
    const float* rp = x_h + (size_t)(b * CH + c0 + cl) * NTOK;
    double s = 0.0;
    for (int i = 0; i < 2; ++i) {
      float4 v = *(const float4*)(rp + (t + 256 * i) * 4);
      s += (double)v.x + (double)v.y + (double)v.z + (double)v.w;
    }
    for (int off = 1; off <= 32; off <<= 1) s += __shfl_xor(s, off);
    if ((t & 63) == 0) red[t >> 6] = s;
    __syncthreads();
    if (t == 0) rowsumH[b * CH + c0 + cl] = red[0] + red[1] + red[2] + red[3];
    __syncthreads();
  }
}

// P[b][c] = sum_d (sum_c' w_qk[d][c'] * rowsumH[b][c']) * w_qk[d][c]   (float64)
__global__ __launch_bounds__(256) void p_kernel(const double* __restrict__ rowsumH,
                                                const float* __restrict__ w_qk,
                                                double* __restrict__ P) {
  const int t = threadIdx.x, b = blockIdx.x;
  __shared__ double Sl[C4];
  if (t < C4) {
    double s = 0.0;
    for (int c = 0; c < CH; ++c) s += (double)w_qk[t * CH + c] * rowsumH[b * CH + c];
    Sl[t] = s;
  }
  __syncthreads();
  if (t < CH) {
    double p = 0.0;
    for (int d = 0; d < C4; ++d) p += Sl[d] * (double)w_qk[d * CH + t];
    P[b * CH + t] = p;
  }
}

// q/k projection: out[b][n][d] = sum_c w_qk[d][c] * src[b][c][n]
// fp32 + bf16-hi + bf16-lo copies, [B][N][32] layout (k-contiguous for MFMA frags)
__global__ __launch_bounds__(256) void prep_qk(const float* __restrict__ x_h,
                                               const float* __restrict__ x_o,
                                               const float* __restrict__ w_qk,
                                               float* __restrict__ xhq_f32,
                                               float* __restrict__ xokT_f32,
                                               unsigned short* __restrict__ xhq_hi,
                                               unsigned short* __restrict__ xokT_hi,
                                               unsigned short* __restrict__ xhq_lo,
                                               unsigned short* __restrict__ xokT_lo) {
  const int t = threadIdx.x;
  const int n0 = blockIdx.x * 64;
  const int b = blockIdx.y;
  const int which = blockIdx.z;
  const float* src = which ? x_o : x_h;
  float* dstf = which ? xokT_f32 : xhq_f32;
  unsigned short* dsth = which ? xokT_hi : xhq_hi;
  unsigned short* dstl = which ? xokT_lo : xhq_lo;

  __shared__ float Xt[CH][64];
  __shared__ float Wl[C4][132];

  for (int i = 0; i < 8; ++i) {
    int flat = t + 256 * i;            // float4 units, 2048 total
    int c = flat >> 4, f4 = flat & 15;
    float4 v = *(const float4*)(src + (size_t)(b * CH + c) * NTOK + n0 + f4 * 4);
    *(float4*)&Xt[c][f4 * 4] = v;
  }
  for (int i = 0; i < 4; ++i) {
    int flat = t + 256 * i;            // float4 units, 1024 total
    int d = flat >> 5, f4 = flat & 31;
    float4 v = *(const float4*)(w_qk + d * CH + f4 * 4);
    *(float4*)&Wl[d][f4 * 4] = v;
  }
  __syncthreads();

  const int nb = (t & 15) * 4;
  const int d0 = (t >> 4) * 2;
  float acc[4][2] = {};
#pragma unroll 4
  for (int c = 0; c < CH; ++c) {
    float4 x4 = *(const float4*)&Xt[c][nb];
    float w0 = Wl[d0][c], w1 = Wl[d0 + 1][c];
    acc[0][0] += x4.x * w0; acc[0][1] += x4.x * w1;
    acc[1][0] += x4.y * w0; acc[1][1] += x4.y * w1;
    acc[2][0] += x4.z * w0; acc[2][1] += x4.z * w1;
    acc[3][0] += x4.w * w0; acc[3][1] += x4.w * w1;
  }

  const size_t robase = (size_t)(b * NTOK + n0 + nb);
#pragma unroll
  for (int i = 0; i < 4; ++i) {
    size_t base = (robase + i) * C4 + d0;
    *(float2*)(dstf + base) = make_float2(acc[i][0], acc[i][1]);
    unsigned short h0 = f2bf(acc[i][0]), h1 = f2bf(acc[i][1]);
    *(unsigned*)(dsth + base) = (unsigned)h0 | ((unsigned)h1 << 16);
    unsigned short l0 = f2bf(acc[i][0] - bf2f(h0));
    unsigned short l1 = f2bf(acc[i][1] - bf2f(h1));
    *(unsigned*)(dstl + base) = (unsigned)l0 | ((unsigned)l1 << 16);
  }
}

// inv[b][m] = 1/(1e-9 + sum_c P[b][c]*x_o[b][c][m])  (float64 dot)
// S2[b][d] += sum_m xo_k[d][m]*inv[m]
__global__ __launch_bounds__(256) void inv_s2(const float* __restrict__ x_o,
                                              const double* __restrict__ P,
                                              const float* __restrict__ xokT_f32,
                                              float* __restrict__ inv,
                                              float* __restrict__ S2) {
  const int t = threadIdx.x;
  const int b = blockIdx.y;
  const int m = blockIdx.x * 256 + t;
  __shared__ double Pl[CH];
  __shared__ float S2l[C4];
  if (t < CH) Pl[t] = P[b * CH + t];
  if (t < C4) S2l[t] = 0.f;
  __syncthreads();
  double cs = 0.0;
  const float* xp = x_o + (size_t)b * CH * NTOK + m;
#pragma unroll 8
  for (int c = 0; c < CH; ++c) cs += Pl[c] * (double)xp[(size_t)c * NTOK];
  float iv = (float)(1.0 / (1e-9 + cs));
  inv[b * NTOK + m] = iv;
  const float* rp = xokT_f32 + (size_t)(b * NTOK + m) * C4;
  for (int dd = 0; dd < C4; ++dd) {
    int d2 = (dd + t) & 31;
    atomicAdd(&S2l[d2], rp[d2] * iv);
  }
  __syncthreads();
  if (t < C4) atomicAdd(&S2[b * C4 + t], S2l[t]);
}

// U[b][d][c'] += sum_m xo_k[d][m]*inv[m]*x_o[b][c'][m]
__global__ __launch_bounds__(256) void u_kernel(const float* __restrict__ x_o,
                                                const float* __restrict__ xokT_f32,
                                                const float* __restrict__ inv,
                                                float* __restrict__ U) {
  const int t = threadIdx.x;
  const int c0 = blockIdx.x * 8;
  const int mbase0 = blockIdx.y * 512;
  const int b = blockIdx.z;
  const int d = t & 31, cl = t >> 5;
  __shared__ float Xs[8][256];
  float acc = 0.f;
  for (int cc = 0; cc < 2; ++cc) {
    const int mb = mbase0 + cc * 256;
    __syncthreads();
    for (int i = 0; i < 2; ++i) {
      int flat = t + 256 * i;          // float4 units, 512 total
      int row = flat >> 6, f4 = flat & 63;
      float4 xv = *(const float4*)(x_o + (size_t)(b * CH + c0 + row) * NTOK + mb + f4 * 4);
      float4 iv = *(const float4*)(inv + b * NTOK + mb + f4 * 4);
      xv.x *= iv.x; xv.y *= iv.y; xv.z *= iv.z; xv.w *= iv.w;
      *(float4*)&Xs[row][f4 * 4] = xv;
    }
    __syncthreads();
    const float* ap = xokT_f32 + (size_t)(b * NTOK + mb) * C4 + d;
#pragma unroll 4
    for (int mm = 0; mm < 256; mm += 4) {
      float4 xq = *(const float4*)&Xs[cl][mm];
      float a0 = ap[(mm + 0) * C4];
      float a1 = ap[(mm + 1) * C4];
      float a2 = ap[(mm + 2) * C4];
      float a3 = ap[(mm + 3) * C4];
      acc += a0 * xq.x + a1 * xq.y + a2 * xq.z + a3 * xq.w;
    }
  }
  atomicAdd(&U[(size_t)(b * C4 + d) * CH + c0 + cl], acc);
}

// T[b][d][c] = sum_c' U[b][d][c']*w_v[c][c'] + S2[b][d]*b_v[c]
__global__ __launch_bounds__(256) void t_kernel(const float* __restrict__ U,
                                                const float* __restrict__ w_v,
                                                const float* __restrict__ b_v,
                                                const float* __restrict__ S2,
                                                float* __restrict__ T) {
  const int t = threadIdx.x, b = blockIdx.x;
  __shared__ float Wl[CH * CH];
  for (int i = 0; i < 16; ++i) {
    int flat = t + 256 * i;            // float4 units, 4096 total
    *(float4*)&Wl[flat * 4] = *(const float4*)(w_v + flat * 4);
  }
  __syncthreads();
  const int d = t & 31;
  const int cg = (t >> 5) * 16;
  float acc[16] = {};
  const float* up = U + (size_t)(b * C4 + d) * CH;
  for (int cp = 0; cp < CH; ++cp) {
    float u = up[cp];
#pragma unroll
    for (int j = 0; j < 16; ++j) acc[j] += u * Wl[(cg + j) * CH + cp];
  }
  float s2 = S2[b * C4 + d];
#pragma unroll
  for (int j = 0; j < 16; ++j) acc[j] += s2 * b_v[cg + j];
  float* tp = T + (size_t)(b * C4 + d) * CH + cg;
#pragma unroll
  for (int j = 0; j < 16; j += 4)
    *(float4*)(tp + j) = make_float4(acc[j], acc[j + 1], acc[j + 2], acc[j + 3]);
}

// out0[b][c][n] = sum_d xh_q[b][n][d] * T[b][d][c]
__global__ __launch_bounds__(256) void xr_kernel(const float* __restrict__ xhq_f32,
                                                 const float* __restrict__ T,
                                                 float* __restrict__ out0) {
  const int t = threadIdx.x;
  const int n = blockIdx.x * 256 + t;
  const int b = blockIdx.y;
  __shared__ float Tl[CH][36];
  for (int i = 0; i < 16; ++i) {
    int flat = t + 256 * i;            // 4096 floats
    int d = flat >> 7, c = flat & 127;
    Tl[c][d] = T[(size_t)b * C4 * CH + flat];
  }
  __syncthreads();
  float xq[C4];
  const float* qp = xhq_f32 + (size_t)(b * NTOK + n) * C4;
#pragma unroll
  for (int i = 0; i < 8; ++i) {
    float4 v = *(const float4*)(qp + i * 4);
    xq[i * 4] = v.x; xq[i * 4 + 1] = v.y; xq[i * 4 + 2] = v.z; xq[i * 4 + 3] = v.w;
  }
  float* op = out0 + (size_t)b * CH * NTOK + n;
  for (int c = 0; c < CH; ++c) {
    float acc = 0.f;
#pragma unroll
    for (int dd = 0; dd < C4; dd += 4) {
      float4 tv = *(const float4*)&Tl[c][dd];
      acc += xq[dd] * tv.x + xq[dd + 1] * tv.y + xq[dd + 2] * tv.z + xq[dd + 3] * tv.w;
    }
    op[(size_t)c * NTOK] = acc;
  }
}

// attention[b][n][m] = (xh_q[n,:] . xo_k[:,m]) * inv[m], bf16 hi/lo split MFMA
__global__ __launch_bounds__(256) void attn_kernel(const unsigned short* __restrict__ xhq_hi,
                                                   const unsigned short* __restrict__ xhq_lo,
                                                   const unsigned short* __restrict__ xokT_hi,
                                                   const unsigned short* __restrict__ xokT_lo,
                                                   const float* __restrict__ inv,
                                                   float* __restrict__ out1) {
  const int t = threadIdx.x;
  const int wave = t >> 6, lane = t & 63;
  const int quad = lane >> 4, l16 = lane & 15;
  const int m0 = blockIdx.x * 64;
  const int n0 = blockIdx.y * 64;
  const int b = blockIdx.z;

  const int n = n0 + wave * 16 + l16;
  const size_t abase = (size_t)(b * NTOK + n) * C4 + quad * 8;
  bf16x8 ah = *(const bf16x8*)(const void*)(xhq_hi + abase);
  bf16x8 al = *(const bf16x8*)(const void*)(xhq_lo + abase);

  bf16x8 bh[4], bl[4];
  float invv[4];
#pragma unroll
  for (int tt = 0; tt < 4; ++tt) {
    int m = m0 + tt * 16 + l16;
    size_t bbase = (size_t)(b * NTOK + m) * C4 + quad * 8;
    bh[tt] = *(const bf16x8*)(const void*)(xokT_hi + bbase);
    bl[tt] = *(const bf16x8*)(const void*)(xokT_lo + bbase);
    invv[tt] = inv[b * NTOK + m];
  }

  const int nrow = n0 + wave * 16 + quad * 4;
#pragma unroll
  for (int tt = 0; tt < 4; ++tt) {
    f32x4 z = {0.f, 0.f, 0.f, 0.f};
    f32x4 acc = __builtin_amdgcn_mfma_f32_16x16x32_bf16(al, bh[tt], z, 0, 0, 0);
    acc = __builtin_amdgcn_mfma_f32_16x16x32_bf16(ah, bl[tt], acc, 0, 0, 0);
    acc = __builtin_amdgcn_mfma_f32_16x16x32_bf16(ah, bh[tt], acc, 0, 0, 0);
#pragma unroll
    for (int r = 0; r < 4; ++r) {
      float v = acc[r] * invv[tt];
      size_t off = ((size_t)(b * NTOK) + nrow + r) * NTOK + m0 + tt * 16 + l16;
      __builtin_nontemporal_store(v, out1 + off);
    }
  }
}

extern "C" void kernel_launch(void* const* d_in, const int* in_sizes, int n_in,
                              void* d_out, int out_size, void* d_ws, size_t ws_size,
                              hipStream_t stream) {
  (void)in_sizes; (void)n_in; (void)out_size; (void)ws_size;
  const float* x_h  = (const float*)d_in[0];
  const float* x_o  = (const float*)d_in[1];
  const float* w_qk = (const float*)d_in[2];
  const float* w_v  = (const float*)d_in[3];
  const float* b_v  = (const float*)d_in[4];
  float* out0 = (float*)d_out;
  float* out1 = out0 + (size_t)NB * CH * NTOK;   // 4,194,304 floats

  char* ws = (char*)d_ws;
  float* xhq_f32        = (float*)(ws + 0);
  float* xokT_f32       = (float*)(ws + 4194304);
  unsigned short* xhq_hi  = (unsigned short*)(ws + 8388608);
  unsigned short* xokT_hi = (unsigned short*)(ws + 10485760);
  unsigned short* xhq_lo  = (unsigned short*)(ws + 12582912);
  unsigned short* xokT_lo = (unsigned short*)(ws + 14680064);
  float* inv      = (float*)(ws + 16777216);
  float* S2       = (float*)(ws + 16908288);   // 2 KB
  float* U        = (float*)(ws + 16910336);   // 256 KB
  float* T        = (float*)(ws + 17172480);   // 256 KB
  double* rowsumH = (double*)(ws + 17434624);  // 16 KB
  double* P       = (double*)(ws + 17450880);  // 16 KB

  // zero the atomic accumulators (S2 + U are contiguous)
  hipMemsetAsync(S2, 0, 2048 + 262144, stream);

  rs_kernel <<<dim3(8, NB), 256, 0, stream>>>(x_h, rowsumH);
  p_kernel  <<<NB, 256, 0, stream>>>(rowsumH, w_qk, P);
  prep_qk   <<<dim3(32, NB, 2), 256, 0, stream>>>(x_h, x_o, w_qk, xhq_f32, xokT_f32,
                                                  xhq_hi, xokT_hi, xhq_lo, xokT_lo);
  inv_s2    <<<dim3(8, NB), 256, 0, stream>>>(x_o, P, xokT_f32, inv, S2);
  u_kernel  <<<dim3(16, 4, NB), 256, 0, stream>>>(x_o, xokT_f32, inv, U);
  t_kernel  <<<NB, 256, 0, stream>>>(U, w_v, b_v, S2, T);
  xr_kernel <<<dim3(8, NB), 256, 0, stream>>>(xhq_f32, T, out0);
  attn_kernel<<<dim3(32, 32, NB), 256, 0, stream>>>(xhq_hi, xhq_lo, xokT_hi, xokT_lo,
                                                    inv, out1);
}